// Round 4
// baseline (572.313 us; speedup 1.0000x reference)
//
#include <hip/hip_runtime.h>

// Problem constants
#define BB 16
#define LL 512
#define DD 512
#define HH 8
#define DKK 64

typedef __attribute__((ext_vector_type(8))) short short8;
typedef __attribute__((ext_vector_type(4))) float floatx4;

__device__ __forceinline__ unsigned short f2bf(float f) {
    unsigned int u = __float_as_uint(f);
    u = u + 0x7FFF + ((u >> 16) & 1);   // round-to-nearest-even
    return (unsigned short)(u >> 16);
}

// load 8 contiguous f32, convert to bf16x8 fragment
__device__ __forceinline__ short8 ldcvt8(const float* p) {
    float4 a = *(const float4*)p;
    float4 b = *(const float4*)(p + 4);
    short8 r;
    r[0] = (short)f2bf(a.x); r[1] = (short)f2bf(a.y);
    r[2] = (short)f2bf(a.z); r[3] = (short)f2bf(a.w);
    r[4] = (short)f2bf(b.x); r[5] = (short)f2bf(b.y);
    r[6] = (short)f2bf(b.z); r[7] = (short)f2bf(b.w);
    return r;
}

// ---------------------------------------------------------------------------
// Mask dtype detector: 0 = 4-byte elems (int32/f32 bool), 1 = 2-byte, 2 = 1-byte.
// ~10% True density over 16KB makes this deterministic.
// ---------------------------------------------------------------------------
__global__ void mask_detect_kernel(const unsigned int* __restrict__ m,
                                   int* __restrict__ flag) {
    int t = threadIdx.x;
    int s2 = 0, s4f = 0, sg1 = 0;
    for (int i = t; i < 4096; i += 64) {
        unsigned int w = m[i];
        if ((w & 0xFFFFu) == 0x3F80u) s2 = 1;       // bf16 "1.0" in low half
        if (w == 0x3F800000u) s4f = 1;              // f32 1.0f
        if (w > 1u) sg1 = 1;                        // not an int32 0/1 word
    }
    unsigned long long b2 = __ballot(s2);
    unsigned long long b4 = __ballot(s4f);
    unsigned long long bg = __ballot(sg1);
    if (t == 0) {
        int f;
        if (b2) f = 1;
        else if (b4) f = 0;
        else if (bg) f = 2;
        else f = 0;
        *flag = f;
    }
}

__device__ __forceinline__ bool mask_at(const void* m, int mflag, size_t idx) {
    if (mflag == 1) return ((const unsigned short*)m)[idx] != 0;
    if (mflag == 2) return ((const unsigned char*)m)[idx] != 0;
    return ((const unsigned int*)m)[idx] != 0;
}

// ---------------------------------------------------------------------------
// Weight transpose + f32->bf16: WT[n][k] = bf16(W[k][n]), 512x512.
// ---------------------------------------------------------------------------
__global__ void wt_kernel(const float* __restrict__ w0,
                          const float* __restrict__ w1,
                          const float* __restrict__ w2,
                          const float* __restrict__ w3,
                          unsigned short* __restrict__ t0,
                          unsigned short* __restrict__ t1,
                          unsigned short* __restrict__ t2,
                          unsigned short* __restrict__ t3) {
    const float* W = blockIdx.z == 0 ? w0 : blockIdx.z == 1 ? w1
                   : blockIdx.z == 2 ? w2 : w3;
    unsigned short* T = blockIdx.z == 0 ? t0 : blockIdx.z == 1 ? t1
                      : blockIdx.z == 2 ? t2 : t3;
    __shared__ unsigned short tile[32][33];
    int x  = blockIdx.x * 32 + threadIdx.x;
    int y0 = blockIdx.y * 32;
    for (int j = threadIdx.y; j < 32; j += 8)
        tile[j][threadIdx.x] = f2bf(W[(size_t)(y0 + j) * DD + x]);
    __syncthreads();
    int ox  = blockIdx.y * 32 + threadIdx.x;
    int oy0 = blockIdx.x * 32;
    for (int j = threadIdx.y; j < 32; j += 8)
        T[(size_t)(oy0 + j) * DD + ox] = tile[threadIdx.x][j];
}

// ---------------------------------------------------------------------------
// Projection GEMM: Y = X @ W.
// INF32: X is float* (convert to bf16 on load) else bf16 ushort*.
// MODE 0: Y bf16 [row*512+col];  MODE 1: Y bf16 vT layout [B,H,DK,L];
// MODE 2: Y f32  [row*512+col]  (final output).
// Block: 256 thr = 4 waves; tile 64(M) x 64(N).
// ---------------------------------------------------------------------------
template <int INF32, int MODE>
__global__ __launch_bounds__(256) void proj_kernel(
        const void* __restrict__ Xv,
        const unsigned short* __restrict__ WT,
        void* __restrict__ Yv) {
    const int lane = threadIdx.x & 63;
    const int wave = threadIdx.x >> 6;
    const int lr = lane & 15;   // A row / B col / D col
    const int kg = lane >> 4;   // k-group
    const int row0 = blockIdx.x * 64 + wave * 16;
    const int col0 = blockIdx.y * 64;

    floatx4 acc[4] = {};
    const size_t xbase = (size_t)(row0 + lr) * DD + kg * 8;
    #pragma unroll 4
    for (int k0 = 0; k0 < 512; k0 += 32) {
        short8 a;
        if (INF32) a = ldcvt8((const float*)Xv + xbase + k0);
        else       a = *(const short8*)((const unsigned short*)Xv + xbase + k0);
        #pragma unroll
        for (int n = 0; n < 4; ++n) {
            const unsigned short* wrow =
                WT + (size_t)(col0 + n * 16 + lr) * DD + k0 + kg * 8;
            short8 b = *(const short8*)wrow;
            acc[n] = __builtin_amdgcn_mfma_f32_16x16x32_bf16(a, b, acc[n], 0, 0, 0);
        }
    }
    #pragma unroll
    for (int n = 0; n < 4; ++n) {
        #pragma unroll
        for (int i = 0; i < 4; ++i) {
            int r = row0 + kg * 4 + i;
            int c = col0 + n * 16 + lr;
            if (MODE == 0) {
                ((unsigned short*)Yv)[(size_t)r * DD + c] = f2bf(acc[n][i]);
            } else if (MODE == 1) {
                int b = r >> 9, l = r & 511;
                int h = c >> 6, dk = c & 63;
                ((unsigned short*)Yv)[((size_t)((b * HH + h) * DKK + dk)) * LL + l]
                    = f2bf(acc[n][i]);
            } else {
                ((float*)Yv)[(size_t)r * DD + c] = acc[n][i];
            }
        }
    }
}

// ---------------------------------------------------------------------------
// Attention: one block per (qt, h, b): 32 q-rows. 4 waves, wave w owns k-cols
// [w*128, w*128+128). Full-row softmax (L=512) with cross-wave LDS reduce.
// p_attn written f32 directly from registers; P kept bf16 in LDS for PV MFMA.
// ---------------------------------------------------------------------------
__global__ __launch_bounds__(256) void attn_kernel(
        const unsigned short* __restrict__ qp,
        const unsigned short* __restrict__ kp,
        const unsigned short* __restrict__ vT,
        const void* __restrict__ mask,
        const int* __restrict__ mflagp,
        const float* __restrict__ aw,
        float* __restrict__ p_out,
        unsigned short* __restrict__ xh) {
    const int qt = blockIdx.x, h = blockIdx.y, b = blockIdx.z;
    const int lane = threadIdx.x & 63;
    const int wave = threadIdx.x >> 6;
    const int lr = lane & 15;
    const int kg = lane >> 4;
    const int q0 = qt * 32;
    const int mflag = *mflagp;   // uniform

    __shared__ unsigned short P[32][520];     // padded stride kills conflicts
    __shared__ float redA[4][32];
    __shared__ float redB[4][32];

    // --- Q fragments ---
    short8 qf[2][2];
    #pragma unroll
    for (int m = 0; m < 2; ++m)
        #pragma unroll
        for (int ks = 0; ks < 2; ++ks)
            qf[m][ks] = *(const short8*)(qp +
                (size_t)(b * LL + q0 + m * 16 + lr) * DD + h * DKK + ks * 32 + kg * 8);

    // --- S = q @ k^T (per wave: 32 x 128) ---
    floatx4 acc[2][8];
    #pragma unroll
    for (int m = 0; m < 2; ++m)
        #pragma unroll
        for (int n = 0; n < 8; ++n) acc[m][n] = (floatx4){0.f, 0.f, 0.f, 0.f};

    #pragma unroll
    for (int n = 0; n < 8; ++n) {
        int kcol = wave * 128 + n * 16 + lr;
        const unsigned short* krow = kp + (size_t)(b * LL + kcol) * DD + h * DKK + kg * 8;
        short8 b0 = *(const short8*)(krow);
        short8 b1 = *(const short8*)(krow + 32);
        #pragma unroll
        for (int m = 0; m < 2; ++m) {
            acc[m][n] = __builtin_amdgcn_mfma_f32_16x16x32_bf16(qf[m][0], b0, acc[m][n], 0, 0, 0);
            acc[m][n] = __builtin_amdgcn_mfma_f32_16x16x32_bf16(qf[m][1], b1, acc[m][n], 0, 0, 0);
        }
    }

    // --- scale + mask + row max (finite sentinel: no NaN possible) ---
    float rmax[2][4];
    #pragma unroll
    for (int m = 0; m < 2; ++m)
        #pragma unroll
        for (int i = 0; i < 4; ++i) rmax[m][i] = -1e30f;

    #pragma unroll
    for (int m = 0; m < 2; ++m) {
        #pragma unroll
        for (int n = 0; n < 8; ++n) {
            int col = wave * 128 + n * 16 + lr;
            #pragma unroll
            for (int i = 0; i < 4; ++i) {
                int row_l = m * 16 + kg * 4 + i;
                bool mk = mask_at(mask, mflag, (size_t)(b * LL + q0 + row_l) * LL + col);
                float s = mk ? -1e30f : acc[m][n][i] * 0.125f;
                acc[m][n][i] = s;
                rmax[m][i] = fmaxf(rmax[m][i], s);
            }
        }
    }
    #pragma unroll
    for (int m = 0; m < 2; ++m)
        #pragma unroll
        for (int i = 0; i < 4; ++i) {
            float v = rmax[m][i];
            v = fmaxf(v, __shfl_xor(v, 1));
            v = fmaxf(v, __shfl_xor(v, 2));
            v = fmaxf(v, __shfl_xor(v, 4));
            v = fmaxf(v, __shfl_xor(v, 8));
            rmax[m][i] = v;
        }
    if (lr == 0) {
        #pragma unroll
        for (int m = 0; m < 2; ++m)
            #pragma unroll
            for (int i = 0; i < 4; ++i) redA[wave][m * 16 + kg * 4 + i] = rmax[m][i];
    }
    __syncthreads();
    #pragma unroll
    for (int m = 0; m < 2; ++m)
        #pragma unroll
        for (int i = 0; i < 4; ++i) {
            int r = m * 16 + kg * 4 + i;
            rmax[m][i] = fmaxf(fmaxf(redA[0][r], redA[1][r]), fmaxf(redA[2][r], redA[3][r]));
        }

    // --- exp + row sum ---
    float rsum[2][4] = {};
    #pragma unroll
    for (int m = 0; m < 2; ++m)
        #pragma unroll
        for (int n = 0; n < 8; ++n)
            #pragma unroll
            for (int i = 0; i < 4; ++i) {
                float e = __expf(acc[m][n][i] - rmax[m][i]);
                acc[m][n][i] = e;
                rsum[m][i] += e;
            }
    #pragma unroll
    for (int m = 0; m < 2; ++m)
        #pragma unroll
        for (int i = 0; i < 4; ++i) {
            float v = rsum[m][i];
            v += __shfl_xor(v, 1);
            v += __shfl_xor(v, 2);
            v += __shfl_xor(v, 4);
            v += __shfl_xor(v, 8);
            rsum[m][i] = v;
        }
    if (lr == 0) {
        #pragma unroll
        for (int m = 0; m < 2; ++m)
            #pragma unroll
            for (int i = 0; i < 4; ++i) redB[wave][m * 16 + kg * 4 + i] = rsum[m][i];
    }
    __syncthreads();

    // --- p = exp/sum * weights -> f32 global + bf16 LDS ---
    #pragma unroll
    for (int m = 0; m < 2; ++m) {
        #pragma unroll
        for (int i = 0; i < 4; ++i) {
            int r = m * 16 + kg * 4 + i;
            float rinv = 1.0f / (redB[0][r] + redB[1][r] + redB[2][r] + redB[3][r]);
            size_t rowbase = ((size_t)((b * HH + h) * LL + q0 + r)) * LL;
            size_t awbase  = ((size_t)(b * LL + q0 + r)) * LL;
            #pragma unroll
            for (int n = 0; n < 8; ++n) {
                int col = wave * 128 + n * 16 + lr;
                float w = aw[awbase + col];
                float p = acc[m][n][i] * rinv * w;
                P[r][col] = f2bf(p);
                p_out[rowbase + col] = p;
            }
        }
    }
    __syncthreads();

    // --- x = P @ v   (per wave: 32 rows x 16 cols, K=512) ---
    floatx4 acc2[2] = {};
    const unsigned short* vrow =
        vT + ((size_t)((b * HH + h) * DKK + wave * 16 + lr)) * LL + kg * 8;
    #pragma unroll 4
    for (int ks = 0; ks < 16; ++ks) {
        short8 bv = *(const short8*)(vrow + ks * 32);
        #pragma unroll
        for (int m = 0; m < 2; ++m) {
            short8 a = *(const short8*)&P[m * 16 + lr][ks * 32 + kg * 8];
            acc2[m] = __builtin_amdgcn_mfma_f32_16x16x32_bf16(a, bv, acc2[m], 0, 0, 0);
        }
    }
    #pragma unroll
    for (int m = 0; m < 2; ++m)
        #pragma unroll
        for (int i = 0; i < 4; ++i) {
            int r = q0 + m * 16 + kg * 4 + i;
            int c = h * DKK + wave * 16 + lr;
            xh[(size_t)(b * LL + r) * DD + c] = f2bf(acc2[m][i]);
        }
}

// ---------------------------------------------------------------------------
extern "C" void kernel_launch(void* const* d_in, const int* in_sizes, int n_in,
                              void* d_out, int out_size, void* d_ws, size_t ws_size,
                              hipStream_t stream) {
    const float* query = (const float*)d_in[0];
    const float* key   = (const float*)d_in[1];
    const float* value = (const float*)d_in[2];
    const void*  mask  = (const void*)d_in[3];
    const float* aw    = (const float*)d_in[4];
    const float* wQ    = (const float*)d_in[5];
    const float* wK    = (const float*)d_in[6];
    const float* wV    = (const float*)d_in[7];
    const float* wfc   = (const float*)d_in[8];

    float* out_x = (float*)d_out;                       // 16*512*512 f32
    float* out_p = out_x + (size_t)BB * LL * DD;        // 16*8*512*512 f32

    unsigned short* ws   = (unsigned short*)d_ws;
    const size_t NBLD = (size_t)BB * LL * DD;           // 4,194,304
    unsigned short* qp   = ws;
    unsigned short* kp   = qp + NBLD;
    unsigned short* vT   = kp + NBLD;
    unsigned short* xh   = vT + NBLD;
    unsigned short* WTq  = xh + NBLD;
    unsigned short* WTk  = WTq + (size_t)DD * DD;
    unsigned short* WTv  = WTk + (size_t)DD * DD;
    unsigned short* WTfc = WTv + (size_t)DD * DD;
    int* mflagp          = (int*)(WTfc + (size_t)DD * DD);

    mask_detect_kernel<<<1, 64, 0, stream>>>((const unsigned int*)mask, mflagp);

    wt_kernel<<<dim3(16, 16, 4), dim3(32, 8), 0, stream>>>(
        wQ, wK, wV, wfc, WTq, WTk, WTv, WTfc);

    proj_kernel<1, 0><<<dim3(128, 8), 256, 0, stream>>>(query, WTq, qp);
    proj_kernel<1, 0><<<dim3(128, 8), 256, 0, stream>>>(key,   WTk, kp);
    proj_kernel<1, 1><<<dim3(128, 8), 256, 0, stream>>>(value, WTv, vT);

    attn_kernel<<<dim3(LL / 32, HH, BB), 256, 0, stream>>>(
        qp, kp, vT, mask, mflagp, aw, out_p, xh);

    proj_kernel<0, 2><<<dim3(128, 8), 256, 0, stream>>>(xh, WTfc, out_x);
}